// Round 5
// baseline (393.326 us; speedup 1.0000x reference)
//
#include <hip/hip_runtime.h>
#include <hip/hip_bf16.h>
#include <cstdint>
#include <cstddef>

// Problem: B=64, L=2048, E=1024, A=512
#define BB   64
#define LL   2048
#define ED   1024
#define AD   512
#define BM   128          // l-rows per block
#define BK   32           // K per step
#define NCH  (LL / BM)    // 16 chunks per batch row
#define KST  (ED / BK)    // 32 K-steps

typedef short  short8  __attribute__((ext_vector_type(8)));
typedef float  f32x4   __attribute__((ext_vector_type(4)));

__device__ __forceinline__ unsigned short f2bf(float x) {
  // round-to-nearest-even fp32 -> bf16
  unsigned u = __float_as_uint(x);
  u += 0x7FFFu + ((u >> 16) & 1u);
  return (unsigned short)(u >> 16);
}

// async global->LDS DMA, 16 bytes per thread (wave-uniform LDS base + lane*16)
#define GLOAD_LDS16(gp, lp)                                                        \
  __builtin_amdgcn_global_load_lds(                                                \
      (const __attribute__((address_space(1))) unsigned int*)(gp),                 \
      (__attribute__((address_space(3))) unsigned int*)(lp), 16, 0, 0)

// ---------------- kernel 0: prep ----------------
// blocks 0..63   : dec_proj row b = dec[b] @ W_dec + b_dec  (coalesced over cols)
// blocks 64..191 : pack W_enc fp32 -> bf16 into the EXACT LDS image order used by
//   fused_kernel (linear o). Decode (within a 16 KB ks-tile):
//   cblk=(o>>9)&31, kg=(o>>7)&3, r=(o>>3)&15, j=o&7 ->
//   k = ks*32 + kg*8 + j ; col = cblk*16 + r
__global__ __launch_bounds__(512) void prep_kernel(
    const float* __restrict__ W_enc, const float* __restrict__ dec,
    const float* __restrict__ W_dec, const float* __restrict__ b_dec,
    unsigned short* __restrict__ Wb, float* __restrict__ dp) {
  const int blk = blockIdx.x, t = threadIdx.x;
  if (blk < BB) {
    const float* drow = dec + blk * ED;
    float a0 = 0.f, a1 = 0.f, a2 = 0.f, a3 = 0.f;
    for (int k = 0; k < ED; k += 4) {
      a0 = fmaf(drow[k],     W_dec[(k)     * AD + t], a0);
      a1 = fmaf(drow[k + 1], W_dec[(k + 1) * AD + t], a1);
      a2 = fmaf(drow[k + 2], W_dec[(k + 2) * AD + t], a2);
      a3 = fmaf(drow[k + 3], W_dec[(k + 3) * AD + t], a3);
    }
    dp[blk * AD + t] = (a0 + a1) + (a2 + a3) + b_dec[t];
  } else {
    const int base = (blk - BB) * 4096;
#pragma unroll
    for (int ii = 0; ii < 8; ii++) {
      const int o    = base + ii * 512 + t;
      const int ks   = o >> 14;
      const int cblk = (o >> 9) & 31;
      const int kg   = (o >> 7) & 3;
      const int r    = (o >> 3) & 15;
      const int j    = o & 7;
      const int k    = ks * 32 + kg * 8 + j;
      const int c    = cblk * 16 + r;
      Wb[o] = f2bf(W_enc[k * AD + c]);
    }
  }
}

// ---------------- kernel 1: fused GEMM + tanh-score + online-softmax partials ----
// grid (NCH, BB), 512 threads = 8 waves as 2M x 4N, wave tile 64 rows x 128 cols.
// ISSUE-LEAD-3 PIPELINE: B quad-buffered via global_load_lds, DMA for tile t+3
// issued at step t; A in 4 named register sets, A(t+3) loaded at step t, cvt'd
// into double-buffered Alds at step t+2's top. Every B-read is transitively
// guarded: cvt of A(t+1) auto-waits loads issued at t-2, which follow B(t+1) in
// issue order -> no explicit vmcnt in the loop, only lgkmcnt(0)+barrier.
__global__ __launch_bounds__(512, 2) void fused_kernel(
    const float* __restrict__ sem, const unsigned short* __restrict__ Wb,
    const float* __restrict__ dp, const float* __restrict__ b_enc,
    const float* __restrict__ Wf,
    float* __restrict__ raw_scores,
    float* __restrict__ ws_ms, float* __restrict__ ws_o) {

  __shared__ unsigned short Alds[2][4096];    // [buf][rblk(8)][kg(4)][16][8]  16 KB
  __shared__ unsigned short Blds[4][16384];   // [buf][cblk(32)][kg(4)][16][8] 128 KB

  const int t    = threadIdx.x;
  const int lane = t & 63;
  const int wave = t >> 6;
  const int wm   = wave >> 2;   // 0..1 row half
  const int wn   = wave & 3;    // 0..3 col quarter
  const int b    = blockIdx.y;
  const int chunk= blockIdx.x;
  const int l0   = chunk * BM;

  // staging mapping
  const int srow = t >> 2;      // 0..127
  const int skg  = t & 3;       // 0..3
  const float* aptr = sem + ((size_t)(b * LL + l0 + srow)) * ED + skg * 8;
  const unsigned short* bsrc = Wb + t * 8;    // + ks*16384 + i*4096
  const int awr = (srow >> 4) * 512 + skg * 128 + (srow & 15) * 8;

  // frag read bases (shorts): wave-contiguous, lane stride 8 shorts = 16 B
  const int arow = lane & 15;
  const int akg  = lane >> 4;
  const int afr  = wm * 2048 + lane * 8;      // + mf*512
  const int bfr  = wn * 4096 + lane * 8;      // + nf*512

  f32x4 acc[4][8];
#pragma unroll
  for (int i = 0; i < 4; i++)
#pragma unroll
    for (int j = 0; j < 8; j++) acc[i][j] = (f32x4)0.f;

  // ---- prologue: B(0..2) DMAs, A(0..2) -> R0..R2, cvt A(0) -> Alds[0] ----
#pragma unroll
  for (int s = 0; s < 3; s++) {
    const unsigned short* bs = bsrc + s * 16384;
#pragma unroll
    for (int i = 0; i < 4; i++)
      GLOAD_LDS16(bs + i * 4096, &Blds[s][i * 4096 + t * 8]);
  }
  __builtin_amdgcn_sched_barrier(0);
  f32x4 R0a = *(const f32x4*)(aptr);
  f32x4 R0b = *(const f32x4*)(aptr + 4);
  f32x4 R1a = *(const f32x4*)(aptr + BK);
  f32x4 R1b = *(const f32x4*)(aptr + BK + 4);
  f32x4 R2a = *(const f32x4*)(aptr + 2 * BK);
  f32x4 R2b = *(const f32x4*)(aptr + 2 * BK + 4);
  f32x4 R3a, R3b;
  {
    short8 aw;   // cvt A(0) (auto vmcnt wait; implies B(0..2) DMAs issued before)
    aw[0]=(short)f2bf(R0a[0]); aw[1]=(short)f2bf(R0a[1]); aw[2]=(short)f2bf(R0a[2]); aw[3]=(short)f2bf(R0a[3]);
    aw[4]=(short)f2bf(R0b[0]); aw[5]=(short)f2bf(R0b[1]); aw[6]=(short)f2bf(R0b[2]); aw[7]=(short)f2bf(R0b[3]);
    *(short8*)&Alds[0][awr] = aw;
  }
  asm volatile("s_waitcnt lgkmcnt(0)" ::: "memory");
  __builtin_amdgcn_sched_barrier(0);
  __builtin_amdgcn_s_barrier();

  // ---- main loop, unrolled x4. Step ks: read B buf[ks%4], A buf[ks%2];
  //      DMA B(ks+3) -> buf[(ks+3)%4]; cvt A(ks+1) -> Alds[(ks+1)%2];
  //      load A(ks+3) -> R[(ks+3)%4].
#define ITER(ks, BRD, BWR, ARD, AWR, CA0, CA1, LA0, LA1)                          \
  {                                                                               \
    if ((ks) + 3 < KST) {                                                         \
      const unsigned short* bs = bsrc + ((ks) + 3) * 16384;                       \
      _Pragma("unroll")                                                           \
      for (int i = 0; i < 4; i++)                                                 \
        GLOAD_LDS16(bs + i * 4096, &Blds[BWR][i * 4096 + t * 8]);                 \
    }                                                                             \
    __builtin_amdgcn_sched_barrier(0);  /* pin: DMAs precede A cvt/loads */       \
    if ((ks) + 1 < KST) {                                                         \
      short8 aw;                                                                  \
      aw[0]=(short)f2bf(CA0[0]); aw[1]=(short)f2bf(CA0[1]);                       \
      aw[2]=(short)f2bf(CA0[2]); aw[3]=(short)f2bf(CA0[3]);                       \
      aw[4]=(short)f2bf(CA1[0]); aw[5]=(short)f2bf(CA1[1]);                       \
      aw[6]=(short)f2bf(CA1[2]); aw[7]=(short)f2bf(CA1[3]);                       \
      *(short8*)&Alds[AWR][awr] = aw;                                             \
    }                                                                             \
    if ((ks) + 3 < KST) {                                                         \
      const float* ap = aptr + ((ks) + 3) * BK;                                   \
      LA0 = *(const f32x4*)(ap);                                                  \
      LA1 = *(const f32x4*)(ap + 4);                                              \
    }                                                                             \
    short8 av[4], bv[8];                                                          \
    _Pragma("unroll")                                                             \
    for (int mf = 0; mf < 4; mf++)                                                \
      av[mf] = *(const short8*)&Alds[ARD][afr + mf * 512];                        \
    _Pragma("unroll")                                                             \
    for (int nf = 0; nf < 8; nf++)                                                \
      bv[nf] = *(const short8*)&Blds[BRD][bfr + nf * 512];                        \
    __builtin_amdgcn_s_setprio(1);                                                \
    _Pragma("unroll")                                                             \
    for (int mf = 0; mf < 4; mf++)                                                \
      _Pragma("unroll")                                                           \
      for (int nf = 0; nf < 8; nf++)                                              \
        acc[mf][nf] = __builtin_amdgcn_mfma_f32_16x16x32_bf16(av[mf], bv[nf], acc[mf][nf], 0, 0, 0); \
    __builtin_amdgcn_s_setprio(0);                                                \
    asm volatile("s_waitcnt lgkmcnt(0)" ::: "memory");  /* A write + own ds_reads drained */ \
    __builtin_amdgcn_sched_barrier(0);                                            \
    __builtin_amdgcn_s_barrier();                                                 \
  }

  for (int kk = 0; kk < KST; kk += 4) {
    ITER(kk,     0, 3, 0, 1, R1a, R1b, R3a, R3b);
    ITER(kk + 1, 1, 0, 1, 0, R2a, R2b, R0a, R0b);
    ITER(kk + 2, 2, 1, 0, 1, R3a, R3b, R1a, R1b);
    ITER(kk + 3, 3, 2, 1, 0, R0a, R0b, R2a, R2b);
  }
#undef ITER

  // ---- epilogue smem carved out of Blds (all B reads done past final barrier) --
  float* eb = (float*)&Blds[0][0];
  float (*sc_part)[4]   = (float (*)[4])eb;            // 128*4
  float* scores_lds     = eb + 512;                    // 128
  float* weight         = eb + 640;                    // 128
  float (*o_lds)[AD]    = (float (*)[AD])(eb + 768);   // 2*512
  float* bcv            = eb + 1792;                   // 2

  // ---- add b_enc, tanh-score, online-softmax partials ----
  float dpv[8], wfv[8], bev[8];
#pragma unroll
  for (int nf = 0; nf < 8; nf++) {
    const int c = wn * 128 + nf * 16 + arow;
    dpv[nf] = dp[b * AD + c];
    wfv[nf] = Wf[c];
    bev[nf] = b_enc[c];
  }
#pragma unroll
  for (int mf = 0; mf < 4; mf++) {
#pragma unroll
    for (int r = 0; r < 4; r++) {
      float p = 0.f;
#pragma unroll
      for (int nf = 0; nf < 8; nf++) {
        float e = acc[mf][nf][r] + bev[nf];
        acc[mf][nf][r] = e;                      // keep enc_proj (+b_enc) for o-accum
        float x = e + dpv[nf];
        float ex = __expf(2.f * x);              // tanh via exp
        float th = 1.f - 2.f / (ex + 1.f);
        p = fmaf(th, wfv[nf], p);
      }
      p += __shfl_xor(p, 1); p += __shfl_xor(p, 2);
      p += __shfl_xor(p, 4); p += __shfl_xor(p, 8);
      if (arow == 0) sc_part[wm * 64 + mf * 16 + akg * 4 + r][wn] = p;
    }
  }
  __syncthreads();

  if (t < BM) {
    float s = sc_part[t][0] + sc_part[t][1] + sc_part[t][2] + sc_part[t][3];
    scores_lds[t] = s;
    raw_scores[(size_t)b * LL + l0 + t] = s;     // raw; finalize normalizes in place
  }
  __syncthreads();
  if (t < 64) {
    float m = fmaxf(scores_lds[t], scores_lds[t + 64]);
#pragma unroll
    for (int off = 1; off < 64; off <<= 1) m = fmaxf(m, __shfl_xor(m, off));
    if (t == 0) bcv[0] = m;
  }
  __syncthreads();
  const float m_c = bcv[0];
  if (t < BM) weight[t] = __expf(scores_lds[t] - m_c);
  __syncthreads();
  if (t < 64) {
    float s = weight[t] + weight[t + 64];
#pragma unroll
    for (int off = 1; off < 64; off <<= 1) s += __shfl_xor(s, off);
    if (t == 0) bcv[1] = s;
  }

  float wv[4][4];
#pragma unroll
  for (int mf = 0; mf < 4; mf++)
#pragma unroll
    for (int r = 0; r < 4; r++) wv[mf][r] = weight[wm * 64 + mf * 16 + akg * 4 + r];
#pragma unroll
  for (int nf = 0; nf < 8; nf++) {
    float cp = 0.f;
#pragma unroll
    for (int mf = 0; mf < 4; mf++)
#pragma unroll
      for (int r = 0; r < 4; r++) cp = fmaf(wv[mf][r], acc[mf][nf][r], cp);
    cp += __shfl_xor(cp, 16);
    cp += __shfl_xor(cp, 32);
    if (lane < 16) o_lds[wm][wn * 128 + nf * 16 + lane] = cp;
  }
  __syncthreads();
  if (t < AD)
    ws_o[((size_t)b * NCH + chunk) * AD + t] = o_lds[0][t] + o_lds[1][t];
  if (t == 0) {
    ws_ms[(b * NCH + chunk) * 2]     = m_c;
    ws_ms[(b * NCH + chunk) * 2 + 1] = bcv[1];
  }
}

// ---------------- kernel 2: finalize (merge chunk partials, normalize) ----------
__global__ __launch_bounds__(256) void finalize_kernel(
    const float* __restrict__ ws_ms, const float* __restrict__ ws_o,
    float* __restrict__ out0, float* __restrict__ outS) {
  const int b = blockIdx.x, t = threadIdx.x;
  float ms[NCH], ss[NCH];
  float M = -1e30f;
#pragma unroll
  for (int i = 0; i < NCH; i++) {
    ms[i] = ws_ms[(b * NCH + i) * 2];
    ss[i] = ws_ms[(b * NCH + i) * 2 + 1];
    M = fmaxf(M, ms[i]);
  }
  float S = 0.f, w[NCH];
#pragma unroll
  for (int i = 0; i < NCH; i++) { w[i] = __expf(ms[i] - M); S = fmaf(ss[i], w[i], S); }
  const float invS = 1.f / S;
  for (int c = t; c < AD; c += 256) {
    float a = 0.f;
#pragma unroll
    for (int i = 0; i < NCH; i++) a = fmaf(ws_o[((size_t)b * NCH + i) * AD + c], w[i], a);
    out0[b * AD + c] = a * invS;
  }
  for (int l = t; l < LL; l += 256) {
    float r = outS[(size_t)b * LL + l];
    outS[(size_t)b * LL + l] = __expf(r - M) * invS;
  }
}

extern "C" void kernel_launch(void* const* d_in, const int* in_sizes, int n_in,
                              void* d_out, int out_size, void* d_ws, size_t ws_size,
                              hipStream_t stream) {
  const float* sem    = (const float*)d_in[0];
  const float* dec    = (const float*)d_in[1];
  const float* W_enc  = (const float*)d_in[2];
  const float* b_enc  = (const float*)d_in[3];
  const float* W_dec  = (const float*)d_in[4];
  const float* b_dec  = (const float*)d_in[5];
  const float* W_full = (const float*)d_in[6];
  // d_in[7] = b_full: constant shift, cancels in softmax.

  float* out0 = (float*)d_out;            // att_output [64][512]
  float* outS = out0 + BB * AD;           // att_scores [64][2048]

  char* ws = (char*)d_ws;
  unsigned short* Wb = (unsigned short*)ws;                          // 1 MB bf16 packed W_enc (LDS image order)
  float* dpw   = (float*)(ws + (1 << 20));                           // 128 KB dec_proj+b_dec
  float* ws_ms = (float*)(ws + (1 << 20) + (128 << 10));             // 16 KB (m,s) per chunk
  float* ws_o  = (float*)(ws + (1 << 20) + (144 << 10));             // 2 MB o partials

  prep_kernel<<<BB + 128, 512, 0, stream>>>(W_enc, dec, W_dec, b_dec, Wb, dpw);
  dim3 g1(NCH, BB);
  fused_kernel<<<g1, 512, 0, stream>>>(sem, Wb, dpw, b_enc, W_full, outS, ws_ms, ws_o);
  finalize_kernel<<<BB, 256, 0, stream>>>(ws_ms, ws_o, out0, outS);
}

// Round 6
// 276.961 us; speedup vs baseline: 1.4202x; 1.4202x over previous
//
#include <hip/hip_runtime.h>
#include <hip/hip_bf16.h>
#include <cstdint>
#include <cstddef>

// Problem: B=64, L=2048, E=1024, A=512
#define BB   64
#define LL   2048
#define ED   1024
#define AD   512
#define BM   128          // l-rows per block
#define NCH  (LL / BM)    // 16 chunks per batch row
#define NBURST 8          // 8 bursts x 128 floats of K each

typedef short  short8  __attribute__((ext_vector_type(8)));
typedef float  f32x4   __attribute__((ext_vector_type(4)));

__device__ __forceinline__ unsigned short f2bf(float x) {
  unsigned u = __float_as_uint(x);
  u += 0x7FFFu + ((u >> 16) & 1u);
  return (unsigned short)(u >> 16);
}

// pack 8 fp32 -> 8 bf16 (RNE) via v_cvt_pk_bf16_f32
__device__ __forceinline__ short8 cvt8(f32x4 lo, f32x4 hi) {
  union { short8 s; unsigned u[4]; } r;
  asm("v_cvt_pk_bf16_f32 %0, %1, %2" : "=v"(r.u[0]) : "v"(lo[0]), "v"(lo[1]));
  asm("v_cvt_pk_bf16_f32 %0, %1, %2" : "=v"(r.u[1]) : "v"(lo[2]), "v"(lo[3]));
  asm("v_cvt_pk_bf16_f32 %0, %1, %2" : "=v"(r.u[2]) : "v"(hi[0]), "v"(hi[1]));
  asm("v_cvt_pk_bf16_f32 %0, %1, %2" : "=v"(r.u[3]) : "v"(hi[2]), "v"(hi[3]));
  return r.s;
}

#define GLOAD_LDS16(gp, lp)                                                        \
  __builtin_amdgcn_global_load_lds(                                                \
      (const __attribute__((address_space(1))) unsigned int*)(gp),                 \
      (__attribute__((address_space(3))) unsigned int*)(lp), 16, 0, 0)

// ---------------- kernel 0: prep ----------------
// blocks 0..63   : dec_proj row b = dec[b] @ W_dec + b_dec
// blocks 64..191 : pack W_enc fp32 -> bf16 in frag-contiguous layout:
//   o = ks*16384 + cblk*512 + kg*128 + r*8 + j  <->  k = ks*32+kg*8+j, col = cblk*16+r
__global__ __launch_bounds__(512) void prep_kernel(
    const float* __restrict__ W_enc, const float* __restrict__ dec,
    const float* __restrict__ W_dec, const float* __restrict__ b_dec,
    unsigned short* __restrict__ Wb, float* __restrict__ dp) {
  const int blk = blockIdx.x, t = threadIdx.x;
  if (blk < BB) {
    const float* drow = dec + blk * ED;
    float a0 = 0.f, a1 = 0.f, a2 = 0.f, a3 = 0.f;
    for (int k = 0; k < ED; k += 4) {
      a0 = fmaf(drow[k],     W_dec[(k)     * AD + t], a0);
      a1 = fmaf(drow[k + 1], W_dec[(k + 1) * AD + t], a1);
      a2 = fmaf(drow[k + 2], W_dec[(k + 2) * AD + t], a2);
      a3 = fmaf(drow[k + 3], W_dec[(k + 3) * AD + t], a3);
    }
    dp[blk * AD + t] = (a0 + a1) + (a2 + a3) + b_dec[t];
  } else {
    const int base = (blk - BB) * 4096;
#pragma unroll
    for (int ii = 0; ii < 8; ii++) {
      const int o    = base + ii * 512 + t;
      const int ks   = o >> 14;
      const int cblk = (o >> 9) & 31;
      const int kg   = (o >> 7) & 3;
      const int r    = (o >> 3) & 15;
      const int j    = o & 7;
      const int k    = ks * 32 + kg * 8 + j;
      const int c    = cblk * 16 + r;
      Wb[o] = f2bf(W_enc[k * AD + c]);
    }
  }
}

// ---------------- kernel 1: fused GEMM + tanh-score + softmax partials ----------
// grid (NCH, BB), 512 threads = 8 waves (2M x 4N), wave tile 64 rows x 128 cols.
// A: fp32, staged in 4-K-step BURSTS of 512-B-contiguous row segments via
//    global_load_lds (fixes DRAM granularity: 512-B bursts instead of 128-B
//    strips). XOR-swizzled source (su = (t&31)^(trow&7)) + matching XOR on the
//    LDS read -> conflict-free fp32 frag reads; cvt to bf16 after the read.
// B: bf16 frags read directly from L2-resident Wb (frag-contiguous layout),
//    no LDS. One barrier per burst (4 K-steps); vmcnt(0) there has ~4 steps of
//    cover for the next-burst DMAs.
__global__ __launch_bounds__(512, 2) void fused_kernel(
    const float* __restrict__ sem, const unsigned short* __restrict__ Wb,
    const float* __restrict__ dp, const float* __restrict__ b_enc,
    const float* __restrict__ Wf,
    float* __restrict__ raw_scores,
    float* __restrict__ ws_ms, float* __restrict__ ws_o) {

  __shared__ float Alds[2][16384];    // [buf][row(128)][32 x f32x4, XOR-swizzled] 128 KB

  const int t    = threadIdx.x;
  const int lane = t & 63;
  const int wave = t >> 6;
  const int wm   = wave >> 2;   // 0..1 row half
  const int wn   = wave & 3;    // 0..3 col quarter
  const int b    = blockIdx.y;
  const int chunk= blockIdx.x;
  const int l0   = chunk * BM;

  // ---- A burst-DMA addressing (pre-swizzled global source) ----
  const int trow = t >> 5;                      // 0..15
  const int su   = (t & 31) ^ (trow & 7);       // per-thread constant swizzle
  const float* asrc = sem + ((size_t)(b * LL + l0 + trow)) * ED + su * 4;
  // DMA j (0..7): + j*16 rows = j*16384 floats ; burst g: + g*128 floats
  // LDS dest: float index j*2048 + t*4  (wave-uniform + lane*16B)

  // ---- A frag read addressing ----
  const int arow = lane & 15;
  const int akg  = lane >> 4;
  const int lxor = lane & 7;
  const int akg2 = akg * 2;
  const int arbase = (wm * 64 + arow) * 128;    // + mf*2048, + slot*4

  // ---- B frag addressing (global, frag-contiguous) ----
  const unsigned short* wbbase = Wb + wn * 4096 + lane * 8;  // + ks*16384 + nf*512

  f32x4 acc[4][8];
#pragma unroll
  for (int i = 0; i < 4; i++)
#pragma unroll
    for (int j = 0; j < 8; j++) acc[i][j] = (f32x4)0.f;

#define STAGE_A(g, nb)                                                             \
  _Pragma("unroll")                                                                \
  for (int j = 0; j < 8; j++)                                                      \
    GLOAD_LDS16(asrc + (size_t)j * 16384 + (g) * 128, &Alds[nb][j * 2048 + t * 4]);

  // ---- prologue: burst 0 ----
  STAGE_A(0, 0);
  asm volatile("s_waitcnt vmcnt(0)" ::: "memory");
  __builtin_amdgcn_sched_barrier(0);
  __builtin_amdgcn_s_barrier();

  // ---- main loop: 8 bursts x 4 K-steps ----
  for (int g = 0; g < NBURST; g++) {
    const int cb = g & 1;
    if (g + 1 < NBURST) STAGE_A(g + 1, cb ^ 1);
    __builtin_amdgcn_sched_barrier(0);   // pin: next-burst DMAs issue first
    const unsigned short* wbg = wbbase + g * 65536;
#pragma unroll
    for (int ks4 = 0; ks4 < 4; ks4++) {
      // B frags straight from L2 (issued early; latency hidden by A reads+cvt)
      short8 bv[8];
#pragma unroll
      for (int nf = 0; nf < 8; nf++)
        bv[nf] = *(const short8*)(wbg + ks4 * 16384 + nf * 512);
      // A frags: fp32 from swizzled LDS, cvt to bf16
      short8 av[4];
#pragma unroll
      for (int mf = 0; mf < 4; mf++) {
        const int s0 = (ks4 * 8 + akg2) ^ lxor;
        const int s1 = (ks4 * 8 + akg2 + 1) ^ lxor;
        f32x4 lo = *(const f32x4*)&Alds[cb][arbase + mf * 2048 + s0 * 4];
        f32x4 hi = *(const f32x4*)&Alds[cb][arbase + mf * 2048 + s1 * 4];
        av[mf] = cvt8(lo, hi);
      }
      __builtin_amdgcn_s_setprio(1);
#pragma unroll
      for (int mf = 0; mf < 4; mf++)
#pragma unroll
        for (int nf = 0; nf < 8; nf++)
          acc[mf][nf] = __builtin_amdgcn_mfma_f32_16x16x32_bf16(av[mf], bv[nf], acc[mf][nf], 0, 0, 0);
      __builtin_amdgcn_s_setprio(0);
    }
    asm volatile("s_waitcnt vmcnt(0) lgkmcnt(0)" ::: "memory");
    __builtin_amdgcn_sched_barrier(0);
    __builtin_amdgcn_s_barrier();
  }
#undef STAGE_A

  // ---- epilogue smem carved out of Alds (all A reads done past final barrier) --
  float* eb = (float*)&Alds[0][0];
  float (*sc_part)[4]   = (float (*)[4])eb;            // 128*4
  float* scores_lds     = eb + 512;                    // 128
  float* weight         = eb + 640;                    // 128
  float (*o_lds)[AD]    = (float (*)[AD])(eb + 768);   // 2*512
  float* bcv            = eb + 1792;                   // 2

  // ---- add b_enc, tanh-score, online-softmax partials ----
  float dpv[8], wfv[8], bev[8];
#pragma unroll
  for (int nf = 0; nf < 8; nf++) {
    const int c = wn * 128 + nf * 16 + arow;
    dpv[nf] = dp[b * AD + c];
    wfv[nf] = Wf[c];
    bev[nf] = b_enc[c];
  }
#pragma unroll
  for (int mf = 0; mf < 4; mf++) {
#pragma unroll
    for (int r = 0; r < 4; r++) {
      float p = 0.f;
#pragma unroll
      for (int nf = 0; nf < 8; nf++) {
        float e = acc[mf][nf][r] + bev[nf];
        acc[mf][nf][r] = e;                      // keep enc_proj (+b_enc) for o-accum
        float x = e + dpv[nf];
        float ex = __expf(2.f * x);              // tanh via exp
        float th = 1.f - 2.f / (ex + 1.f);
        p = fmaf(th, wfv[nf], p);
      }
      p += __shfl_xor(p, 1); p += __shfl_xor(p, 2);
      p += __shfl_xor(p, 4); p += __shfl_xor(p, 8);
      if (arow == 0) sc_part[wm * 64 + mf * 16 + akg * 4 + r][wn] = p;
    }
  }
  __syncthreads();

  if (t < BM) {
    float s = sc_part[t][0] + sc_part[t][1] + sc_part[t][2] + sc_part[t][3];
    scores_lds[t] = s;
    raw_scores[(size_t)b * LL + l0 + t] = s;     // raw; finalize normalizes in place
  }
  __syncthreads();
  if (t < 64) {
    float m = fmaxf(scores_lds[t], scores_lds[t + 64]);
#pragma unroll
    for (int off = 1; off < 64; off <<= 1) m = fmaxf(m, __shfl_xor(m, off));
    if (t == 0) bcv[0] = m;
  }
  __syncthreads();
  const float m_c = bcv[0];
  if (t < BM) weight[t] = __expf(scores_lds[t] - m_c);
  __syncthreads();
  if (t < 64) {
    float s = weight[t] + weight[t + 64];
#pragma unroll
    for (int off = 1; off < 64; off <<= 1) s += __shfl_xor(s, off);
    if (t == 0) bcv[1] = s;
  }

  float wv[4][4];
#pragma unroll
  for (int mf = 0; mf < 4; mf++)
#pragma unroll
    for (int r = 0; r < 4; r++) wv[mf][r] = weight[wm * 64 + mf * 16 + akg * 4 + r];
#pragma unroll
  for (int nf = 0; nf < 8; nf++) {
    float cp = 0.f;
#pragma unroll
    for (int mf = 0; mf < 4; mf++)
#pragma unroll
      for (int r = 0; r < 4; r++) cp = fmaf(wv[mf][r], acc[mf][nf][r], cp);
    cp += __shfl_xor(cp, 16);
    cp += __shfl_xor(cp, 32);
    if (lane < 16) o_lds[wm][wn * 128 + nf * 16 + lane] = cp;
  }
  __syncthreads();
  if (t < AD)
    ws_o[((size_t)b * NCH + chunk) * AD + t] = o_lds[0][t] + o_lds[1][t];
  if (t == 0) {
    ws_ms[(b * NCH + chunk) * 2]     = m_c;
    ws_ms[(b * NCH + chunk) * 2 + 1] = bcv[1];
  }
}

// ---------------- kernel 2: finalize (merge chunk partials, normalize) ----------
__global__ __launch_bounds__(256) void finalize_kernel(
    const float* __restrict__ ws_ms, const float* __restrict__ ws_o,
    float* __restrict__ out0, float* __restrict__ outS) {
  const int b = blockIdx.x, t = threadIdx.x;
  float ms[NCH], ss[NCH];
  float M = -1e30f;
#pragma unroll
  for (int i = 0; i < NCH; i++) {
    ms[i] = ws_ms[(b * NCH + i) * 2];
    ss[i] = ws_ms[(b * NCH + i) * 2 + 1];
    M = fmaxf(M, ms[i]);
  }
  float S = 0.f, w[NCH];
#pragma unroll
  for (int i = 0; i < NCH; i++) { w[i] = __expf(ms[i] - M); S = fmaf(ss[i], w[i], S); }
  const float invS = 1.f / S;
  for (int c = t; c < AD; c += 256) {
    float a = 0.f;
#pragma unroll
    for (int i = 0; i < NCH; i++) a = fmaf(ws_o[((size_t)b * NCH + i) * AD + c], w[i], a);
    out0[b * AD + c] = a * invS;
  }
  for (int l = t; l < LL; l += 256) {
    float r = outS[(size_t)b * LL + l];
    outS[(size_t)b * LL + l] = __expf(r - M) * invS;
  }
}

extern "C" void kernel_launch(void* const* d_in, const int* in_sizes, int n_in,
                              void* d_out, int out_size, void* d_ws, size_t ws_size,
                              hipStream_t stream) {
  const float* sem    = (const float*)d_in[0];
  const float* dec    = (const float*)d_in[1];
  const float* W_enc  = (const float*)d_in[2];
  const float* b_enc  = (const float*)d_in[3];
  const float* W_dec  = (const float*)d_in[4];
  const float* b_dec  = (const float*)d_in[5];
  const float* W_full = (const float*)d_in[6];
  // d_in[7] = b_full: constant shift, cancels in softmax.

  float* out0 = (float*)d_out;            // att_output [64][512]
  float* outS = out0 + BB * AD;           // att_scores [64][2048]

  char* ws = (char*)d_ws;
  unsigned short* Wb = (unsigned short*)ws;                          // 1 MB bf16 packed W_enc
  float* dpw   = (float*)(ws + (1 << 20));                           // 128 KB dec_proj+b_dec
  float* ws_ms = (float*)(ws + (1 << 20) + (128 << 10));             // 8 KB (m,s) per chunk
  float* ws_o  = (float*)(ws + (1 << 20) + (136 << 10));             // 2 MB o partials

  prep_kernel<<<BB + 128, 512, 0, stream>>>(W_enc, dec, W_dec, b_dec, Wb, dpw);
  dim3 g1(NCH, BB);
  fused_kernel<<<g1, 512, 0, stream>>>(sem, Wb, dpw, b_enc, W_full, outS, ws_ms, ws_o);
  finalize_kernel<<<BB, 256, 0, stream>>>(ws_ms, ws_o, out0, outS);
}